// Round 1
// baseline (3281.698 us; speedup 1.0000x reference)
//
#include <hip/hip_runtime.h>

typedef unsigned short u16;
typedef unsigned int u32;
typedef short bf16x8 __attribute__((ext_vector_type(8)));
typedef float f32x4 __attribute__((ext_vector_type(4)));

#define B_ 16
#define T_ 128
#define H_ 512
#define V_ 32000
#define G3 1536
#define STEPS 127

// ---------------- ws layout (float units) ----------------
#define OFF_VT    0u            // [2048][512]  m=b*128+t
#define OFF_P     1048576u      // [2048][1536] m=b*128+t
#define OFF_GIX   4194304u      // [2048][1536] m=s*16+b
#define OFF_HALL  7340032u      // [2048][512]  m=s*16+b
#define OFF_PART  8388608u      // [256][128] score partials (reuses old Q/GH region)
#define OFF_BAR   8423424u      // 512 u32: 16 groups x 32-u32 stride (own line each)
#define OFF_AENC  8431616u      // bf16 [2048][512]
#define OFF_AEMB  8955904u
#define OFF_AH    9480192u
#define OFF_BWV   10004480u     // bf16 [512][512]
#define OFF_BWIH1 10135552u     // bf16 [1536][512]
#define OFF_BWIH2 10528768u
#define OFF_BWO   10921984u     // bf16 [32000][512]

__device__ __forceinline__ u16 f2bf(float f) {
  union { float f; u32 u; } x; x.f = f;
  u32 r = x.u + 0x7fffu + ((x.u >> 16) & 1u);
  return (u16)(r >> 16);
}
__device__ __forceinline__ float bf2f(u16 u) {
  union { u32 u; float f; } x; x.u = ((u32)u) << 16;
  return x.f;
}
__device__ __forceinline__ float wred(float v) {
#pragma unroll
  for (int off = 32; off > 0; off >>= 1) v += __shfl_down(v, off, 64);
  return v; // valid in lane 0
}

// MALL-coherent scalar exchange: relaxed agent-scope atomics bypass stale
// L1/per-XCD-L2 and serialize at the Infinity Cache. No fences needed.
__device__ __forceinline__ void st_sys(float* p, float v) {
  __hip_atomic_store(p, v, __ATOMIC_RELAXED, __HIP_MEMORY_SCOPE_AGENT);
}
__device__ __forceinline__ float ld_sys(const float* p) {
  return __hip_atomic_load(p, __ATOMIC_RELAXED, __HIP_MEMORY_SCOPE_AGENT);
}

// ---------------- small utility kernels ----------------
__global__ void k_init(float* __restrict__ out, u32* __restrict__ bars) {
  int idx = blockIdx.x * 256 + threadIdx.x;
  if (idx < 512000) {            // out[:,0,:] = 0
    int b = idx / 32000; int v = idx - b * 32000;
    out[(size_t)b * 4096000 + v] = 0.f;
  }
  if (idx < 512) bars[idx] = 0u;
}

__global__ void k_f2bf(const float* __restrict__ src, u16* __restrict__ dst, int n) {
  int idx = blockIdx.x * 256 + threadIdx.x;
  if (idx < n) dst[idx] = f2bf(src[idx]);
}

// take 512-wide column slice [off, off+512) of rows with leading dim ld
__global__ void k_f2bf_sub(const float* __restrict__ src, u16* __restrict__ dst,
                           int n, int ld, int off) {
  int idx = blockIdx.x * 256 + threadIdx.x;
  if (idx < n) {
    int r = idx >> 9, c = idx & 511;
    dst[idx] = f2bf(src[(size_t)r * ld + off + c]);
  }
}

// A_emb[m= s*16+b][c] = bf16(emb[tok(b,s)][c]), tok = s==0 ? BOS(1) : target[b][s]
__global__ void k_gather(const float* __restrict__ emb, const int* __restrict__ tgt,
                         u16* __restrict__ dst, int n) {
  int idx = blockIdx.x * 256 + threadIdx.x;
  if (idx < n) {
    int m = idx >> 9, c = idx & 511;
    int b = m & 15, s = m >> 4;
    int tok = (s == 0) ? 1 : tgt[b * 128 + s];
    dst[idx] = f2bf(emb[(size_t)tok * 512 + c]);
  }
}

// ---------------- bf16 MFMA GEMM: C[m][n] = sum_k A[m][k]*B[n][k] + bias[n] ----------------
__global__ __launch_bounds__(256) void gemm_bf16(
    const u16* __restrict__ A, const u16* __restrict__ Bm,
    const float* __restrict__ bias, float* __restrict__ C,
    int ldc, int mode) {
  __shared__ u16 As[128 * 32];
  __shared__ u16 Bs[128 * 32];
  const int tid = threadIdx.x;
  const int lane = tid & 63;
  const int wave = tid >> 6;
  const int lr = lane & 15;
  const int quad = lane >> 4;
  const int wm = (wave >> 1) * 64;
  const int wn = (wave & 1) * 64;
  const int bm = blockIdx.y * 128;
  const int bn = blockIdx.x * 128;
  const int srow = tid >> 1;          // 0..127
  const int shalf = (tid & 1) * 16;   // 0 or 16

  f32x4 acc[4][4];
#pragma unroll
  for (int i = 0; i < 4; ++i)
#pragma unroll
    for (int j = 0; j < 4; ++j) acc[i][j] = (f32x4){0.f, 0.f, 0.f, 0.f};

  for (int kt = 0; kt < 16; ++kt) {
    const u16* gA = A + (size_t)(bm + srow) * 512 + kt * 32 + shalf;
    const u16* gB = Bm + (size_t)(bn + srow) * 512 + kt * 32 + shalf;
    uint4 a0 = *(const uint4*)gA;
    uint4 a1 = *(const uint4*)(gA + 8);
    uint4 b0 = *(const uint4*)gB;
    uint4 b1 = *(const uint4*)(gB + 8);
    __syncthreads();
    *(uint4*)&As[srow * 32 + shalf] = a0;
    *(uint4*)&As[srow * 32 + shalf + 8] = a1;
    *(uint4*)&Bs[srow * 32 + shalf] = b0;
    *(uint4*)&Bs[srow * 32 + shalf + 8] = b1;
    __syncthreads();
    bf16x8 af[4], bf[4];
#pragma unroll
    for (int i = 0; i < 4; ++i)
      af[i] = *(const bf16x8*)&As[(wm + i * 16 + lr) * 32 + quad * 8];
#pragma unroll
    for (int j = 0; j < 4; ++j)
      bf[j] = *(const bf16x8*)&Bs[(wn + j * 16 + lr) * 32 + quad * 8];
#pragma unroll
    for (int i = 0; i < 4; ++i)
#pragma unroll
      for (int j = 0; j < 4; ++j)
        acc[i][j] = __builtin_amdgcn_mfma_f32_16x16x32_bf16(af[i], bf[j], acc[i][j], 0, 0, 0);
  }

#pragma unroll
  for (int j = 0; j < 4; ++j) {
    int ng = bn + wn + j * 16 + lr;
    float bv = bias ? bias[ng] : 0.f;
#pragma unroll
    for (int i = 0; i < 4; ++i) {
      int mg0 = bm + wm + i * 16 + quad * 4;
#pragma unroll
      for (int r = 0; r < 4; ++r) {
        int mg = mg0 + r;
        float v = acc[i][j][r] + bv;
        if (mode == 0) {
          C[(size_t)mg * ldc + ng] = v;
        } else {
          if (mg < 2032) {
            int s = mg >> 4, b = mg & 15;
            C[(size_t)((b << 7) + s + 1) * 32000 + ng] = v;
          }
        }
      }
    }
  }
}

// ---------------- group-local (16-block) barrier ----------------
// Same fence discipline as the proven global gbar: compiler drains vmcnt
// before s_barrier, thread0 re-drains + stores its flag at agent scope
// (MALL-coherent), wave 0 polls the group's 16 flags (one cache line).
__device__ __forceinline__ void gbar_g(u32* gb, int j, u32 phase) {
  __syncthreads();   // all waves' sc0sc1 stores drained at MALL
  if (threadIdx.x == 0) {
    asm volatile("s_waitcnt vmcnt(0)" ::: "memory");
    __hip_atomic_store(&gb[j], phase, __ATOMIC_RELAXED, __HIP_MEMORY_SCOPE_AGENT);
  }
  if (threadIdx.x < 64) {
    for (;;) {
      u32 v = __hip_atomic_load(&gb[threadIdx.x & 15], __ATOMIC_RELAXED, __HIP_MEMORY_SCOPE_AGENT);
      if (__all(v >= phase)) break;
      __builtin_amdgcn_s_sleep(1);
    }
  }
  asm volatile("" ::: "memory");
  __syncthreads();
}

// ---------------- sequential decoder: 16 independent per-batch groups ----------------
// Group = 16 blocks sharing batch b (b = blockIdx.x>>4, member j = blockIdx.x&15).
// Block j owns: q rows [32j,32j+32), the matching rank-32 score partials for all
// 128 t, the 96 Whh rows its own GRU slice needs, and h slice [32j,32j+32).
// Per step: PhaseA(local q/gh/partials) -> group bar -> PhaseB(sum partials,
// softmax, ctx, GRU, write h slice) -> group bar.  Only h (512 f) and partials
// (16x128 f) cross blocks, and only within the group.
__global__ __launch_bounds__(256, 1) void seq_kernel(
    const float* __restrict__ Wq, const float* __restrict__ bq,
    const float* __restrict__ Wc, const float* __restrict__ bc,
    const float* __restrict__ Whh, const float* __restrict__ bhh,
    const float* __restrict__ h0, const int* __restrict__ mask,
    const float* __restrict__ ws_vt, const float* __restrict__ ws_P,
    const float* __restrict__ ws_gix, float* __restrict__ ws_hall,
    float* __restrict__ ws_part, u32* __restrict__ bars,
    float* __restrict__ outT) {
  const int k = blockIdx.x;        // 0..255
  const int b = k >> 4;            // batch
  const int j = k & 15;            // group member
  const int i0 = j << 5;           // h-slice / q-row-slice base
  const int tid = threadIdx.x;
  const int lane = tid & 63;
  const int wv = tid >> 6;

  __shared__ u16 P_lds[128][96];   // 24 KB  P[b][t][jg-slice] bf16
  __shared__ float vt_s[32][128];  // 16 KB  vt[b][t][i0+rr] (transposed)
  __shared__ float h_l[512];
  __shared__ float q_l[32];
  __shared__ float gh_l[96];
  __shared__ float gi_l[96];
  __shared__ float s_lds[128];
  __shared__ float p_lds[128];
  __shared__ float Wc_s[32];
  __shared__ float bq_s[32];
  __shared__ float bhh_s[96];
  __shared__ int   m_l[128];

  // ---- step-invariant preloads ----
  // wave 0: 32 Wq rows (q slice); waves 1..3: 32 Whh rows each (gates r,z,n slice)
  float Wreg[32][8];   // lane's K-slice (8 f32) of each of this wave's 32 rows
#pragma unroll
  for (int rr = 0; rr < 32; ++rr) {
    const float* wp = (wv == 0) ? (Wq + (size_t)(i0 + rr) * 512)
                                : (Whh + (size_t)((wv - 1) * 512 + i0 + rr) * 512);
    const float4* w4 = (const float4*)(wp + (lane << 3));
    float4 a = w4[0], c = w4[1];
    Wreg[rr][0] = a.x; Wreg[rr][1] = a.y; Wreg[rr][2] = a.z; Wreg[rr][3] = a.w;
    Wreg[rr][4] = c.x; Wreg[rr][5] = c.y; Wreg[rr][6] = c.z; Wreg[rr][7] = c.w;
  }
  if (tid < 32) { Wc_s[tid] = Wc[i0 + tid]; bq_s[tid] = bq[i0 + tid]; }
  if (tid < 96) bhh_s[tid] = bhh[(tid >> 5) * 512 + i0 + (tid & 31)];
  if (tid < 128) m_l[tid] = mask[(b << 7) + tid];
  for (int idx = tid; idx < 128 * 96; idx += 256) {
    int t = idx / 96; int jj = idx - t * 96;
    int col = (jj >> 5) * 512 + i0 + (jj & 31);
    P_lds[t][jj] = f2bf(ws_P[(size_t)((b << 7) + t) * 1536 + col]);
  }
  for (int idx = tid; idx < 32 * 128; idx += 256) {
    int rr = idx >> 7, t = idx & 127;
    vt_s[rr][t] = ws_vt[(size_t)((b << 7) + t) * 512 + i0 + rr];
  }
  const float bc0 = bc[0];
  __syncthreads();

  u32* gb = bars + (b << 5);       // this group's private flag line
  u32 phase = 0;
  for (int s = 0; s < STEPS; ++s) {
    // ---- Phase A: load full h[b], local q-slice + gh-slice + score partials ----
    const float* hbase = (s == 0) ? (h0 + (b << 9))
                                  : (ws_hall + (size_t)(((s - 1) << 4) + b) * 512);
    for (int i = tid; i < 512; i += 256) h_l[i] = ld_sys(hbase + i);
    __syncthreads();
    float hk[8];
    {
      const float4* h4 = (const float4*)&h_l[lane << 3];
      float4 a = h4[0], c = h4[1];
      hk[0] = a.x; hk[1] = a.y; hk[2] = a.z; hk[3] = a.w;
      hk[4] = c.x; hk[5] = c.y; hk[6] = c.z; hk[7] = c.w;
    }
#pragma unroll
    for (int rr = 0; rr < 32; ++rr) {
      float p = Wreg[rr][0] * hk[0] + Wreg[rr][1] * hk[1]
              + Wreg[rr][2] * hk[2] + Wreg[rr][3] * hk[3]
              + Wreg[rr][4] * hk[4] + Wreg[rr][5] * hk[5]
              + Wreg[rr][6] * hk[6] + Wreg[rr][7] * hk[7];
      p = wred(p);
      if (lane == 0) {
        if (wv == 0) q_l[rr] = p;                                   // bias added at use
        else gh_l[((wv - 1) << 5) + rr] = p + bhh_s[((wv - 1) << 5) + rr];
      }
    }
    __syncthreads();
    {
      // rank-32 score partials: 2 threads per t, 16 tanh each
      int t = tid >> 1, rh = (tid & 1) << 4;
      float part = 0.f;
#pragma unroll
      for (int u = 0; u < 16; ++u) {
        int rr = rh + u;
        part += Wc_s[rr] * tanhf(q_l[rr] + bq_s[rr] + vt_s[rr][t]);
      }
      part += __shfl_xor(part, 1, 64);
      if (!(tid & 1)) st_sys(&ws_part[(size_t)(((b << 4) + j) << 7) + t], part);
    }
    gbar_g(gb, j, ++phase);

    // ---- Phase B: assemble scores, softmax, ctx, GRU update for my slice ----
    {
      int t = tid >> 1;
      int ib = (tid & 1) << 3;     // 2 threads per t, 8 partials each
      float sum = 0.f;
#pragma unroll
      for (int u = 0; u < 8; ++u)
        sum += ld_sys(&ws_part[(size_t)(((b << 4) + ib + u) << 7) + t]);
      sum += __shfl_xor(sum, 1, 64);
      if (!(tid & 1))
        s_lds[t] = m_l[t] ? (sum + bc0) : -3.4028234663852886e+38f;
    }
    __syncthreads();
    float vm = fmaxf(s_lds[lane], s_lds[64 + lane]);
#pragma unroll
    for (int mo = 32; mo > 0; mo >>= 1) vm = fmaxf(vm, __shfl_xor(vm, mo, 64));
    if (tid < 128) p_lds[tid] = expf(s_lds[tid] - vm);
    __syncthreads();
    float vs = p_lds[lane] + p_lds[64 + lane];
#pragma unroll
    for (int mo = 32; mo > 0; mo >>= 1) vs += __shfl_xor(vs, mo, 64);
    float rsum = 1.0f / vs;
    if (tid < 96) {
      int jg = (tid >> 5) * 512 + i0 + (tid & 31);
      float acc = 0.f;
#pragma unroll 8
      for (int t = 0; t < 128; ++t) acc += p_lds[t] * bf2f(P_lds[t][tid]);
      gi_l[tid] = ws_gix[(size_t)((s << 4) + b) * 1536 + jg] + acc * rsum;
    }
    __syncthreads();
    if (tid < 32) {
      float rg = 1.f / (1.f + expf(-(gi_l[tid] + gh_l[tid])));
      float zg = 1.f / (1.f + expf(-(gi_l[32 + tid] + gh_l[32 + tid])));
      float ng = tanhf(gi_l[64 + tid] + rg * gh_l[64 + tid]);
      float hold = h_l[i0 + tid];
      float hn = (1.f - zg) * ng + zg * hold;
      st_sys(&ws_hall[(size_t)((s << 4) + b) * 512 + i0 + tid], hn);
    }
    gbar_g(gb, j, ++phase);
  }

  // hT output: member 0 of each group writes its batch's final h
  if (j == 0) {
    for (int i = tid; i < 512; i += 256)
      outT[(b << 9) + i] = ld_sys(&ws_hall[(size_t)(126 * 16 + b) * 512 + i]);
  }
}

// ---------------- launch ----------------
extern "C" void kernel_launch(void* const* d_in, const int* in_sizes, int n_in,
                              void* d_out, int out_size, void* d_ws, size_t ws_size,
                              hipStream_t stream) {
  const float* enc  = (const float*)d_in[0];
  const float* ehid = (const float*)d_in[1];
  const int*   mask = (const int*)d_in[2];
  const int*   tgt  = (const int*)d_in[3];
  const float* emb  = (const float*)d_in[4];
  const float* Wq   = (const float*)d_in[5];
  const float* bq   = (const float*)d_in[6];
  const float* Wv   = (const float*)d_in[7];
  const float* bv   = (const float*)d_in[8];
  const float* Wc   = (const float*)d_in[9];
  const float* bc   = (const float*)d_in[10];
  const float* Wih  = (const float*)d_in[11];
  const float* Whh  = (const float*)d_in[12];
  const float* bih  = (const float*)d_in[13];
  const float* bhh  = (const float*)d_in[14];
  const float* Wo   = (const float*)d_in[15];
  const float* bo   = (const float*)d_in[16];

  float* out = (float*)d_out;
  float* ws  = (float*)d_ws;
  float* vt   = ws + OFF_VT;
  float* P    = ws + OFF_P;
  float* gix  = ws + OFF_GIX;
  float* hall = ws + OFF_HALL;
  float* part = ws + OFF_PART;
  u32*   bars = (u32*)(ws + OFF_BAR);
  u16* A_enc = (u16*)(ws + OFF_AENC);
  u16* A_emb = (u16*)(ws + OFF_AEMB);
  u16* A_h   = (u16*)(ws + OFF_AH);
  u16* B_wv  = (u16*)(ws + OFF_BWV);
  u16* B_wi1 = (u16*)(ws + OFF_BWIH1);
  u16* B_wi2 = (u16*)(ws + OFF_BWIH2);
  u16* B_wo  = (u16*)(ws + OFF_BWO);

  k_init<<<2000, 256, 0, stream>>>(out, bars);
  k_f2bf<<<4096, 256, 0, stream>>>(enc, A_enc, 1048576);
  k_f2bf<<<1024, 256, 0, stream>>>(Wv, B_wv, 262144);
  k_f2bf_sub<<<3072, 256, 0, stream>>>(Wih, B_wi1, 786432, 1024, 0);
  k_f2bf_sub<<<3072, 256, 0, stream>>>(Wih, B_wi2, 786432, 1024, 512);
  k_f2bf<<<64000, 256, 0, stream>>>(Wo, B_wo, 16384000);
  k_gather<<<4064, 256, 0, stream>>>(emb, tgt, A_emb, 1040384);

  // vt = enc @ Wv.T + bv            [2048 x 512]
  gemm_bf16<<<dim3(4, 16), 256, 0, stream>>>(A_enc, B_wv, bv, vt, 512, 0);
  // P  = enc @ Wih[:,H:].T          [2048 x 1536]
  gemm_bf16<<<dim3(12, 16), 256, 0, stream>>>(A_enc, B_wi2, nullptr, P, 1536, 0);
  // gi_x = emb[toks] @ Wih[:,:H].T + bih   [2032 x 1536]
  gemm_bf16<<<dim3(12, 16), 256, 0, stream>>>(A_emb, B_wi1, bih, gix, 1536, 0);

  seq_kernel<<<256, 256, 0, stream>>>(Wq, bq, Wc, bc, Whh, bhh,
                                      ehid, mask, vt, P, gix, hall, part, bars,
                                      out + 65536000);

  k_f2bf<<<4064, 256, 0, stream>>>(hall, A_h, 1040384);
  // logits = h_all @ Wo.T + bo -> out[:,1:,:]
  gemm_bf16<<<dim3(250, 16), 256, 0, stream>>>(A_h, B_wo, bo, out, 32000, 1);
}

// Round 2
// 2733.108 us; speedup vs baseline: 1.2007x; 1.2007x over previous
//
#include <hip/hip_runtime.h>

typedef unsigned short u16;
typedef unsigned int u32;
typedef short bf16x8 __attribute__((ext_vector_type(8)));
typedef float f32x4 __attribute__((ext_vector_type(4)));

#define B_ 16
#define T_ 128
#define H_ 512
#define V_ 32000
#define G3 1536
#define STEPS 127

// ---------------- ws layout (float units) ----------------
#define OFF_VT    0u            // [2048][512]  m=b*128+t
#define OFF_P     1048576u      // [2048][1536] m=b*128+t
#define OFF_GIX   4194304u      // [2048][1536] m=s*16+b
#define OFF_HALL  7340032u      // [2048][512]  m=s*16+b
#define OFF_PART  8388608u      // [256][128] score partials
#define OFF_BAR   8423424u      // 512 u32: 16 groups x 32-u32 stride (own line each)
#define OFF_AENC  8431616u      // bf16 [2048][512]
#define OFF_AEMB  8955904u
#define OFF_AH    9480192u
#define OFF_BWV   10004480u     // bf16 [512][512]
#define OFF_BWIH1 10135552u     // bf16 [1536][512]
#define OFF_BWIH2 10528768u
#define OFF_BWO   10921984u     // bf16 [32000][512]

__device__ __forceinline__ u16 f2bf(float f) {
  union { float f; u32 u; } x; x.f = f;
  u32 r = x.u + 0x7fffu + ((x.u >> 16) & 1u);
  return (u16)(r >> 16);
}
__device__ __forceinline__ float bf2f(u16 u) {
  union { u32 u; float f; } x; x.u = ((u32)u) << 16;
  return x.f;
}
__device__ __forceinline__ float wred(float v) {
#pragma unroll
  for (int off = 32; off > 0; off >>= 1) v += __shfl_down(v, off, 64);
  return v; // valid in lane 0
}
// fast tanh via v_exp_f32: tanh(x) = (e^{2x}-1)/(e^{2x}+1), clamped
__device__ __forceinline__ float tanh_fast(float x) {
  float cx = fminf(8.f, fmaxf(-8.f, x));
  float e = __expf(2.f * cx);
  return (e - 1.f) / (e + 1.f);
}
__device__ __forceinline__ float sigmoid_fast(float x) {
  return 1.f / (1.f + __expf(-x));
}

// MALL-coherent scalar exchange: relaxed agent-scope atomics bypass stale
// L1/per-XCD-L2 and serialize at the Infinity Cache. No fences needed.
__device__ __forceinline__ void st_sys(float* p, float v) {
  __hip_atomic_store(p, v, __ATOMIC_RELAXED, __HIP_MEMORY_SCOPE_AGENT);
}
__device__ __forceinline__ float ld_sys(const float* p) {
  return __hip_atomic_load(p, __ATOMIC_RELAXED, __HIP_MEMORY_SCOPE_AGENT);
}

// ---------------- small utility kernels ----------------
__global__ void k_init(float* __restrict__ out, u32* __restrict__ bars) {
  int idx = blockIdx.x * 256 + threadIdx.x;
  if (idx < 512000) {            // out[:,0,:] = 0
    int b = idx / 32000; int v = idx - b * 32000;
    out[(size_t)b * 4096000 + v] = 0.f;
  }
  if (idx < 512) bars[idx] = 0u;
}

__global__ void k_f2bf(const float* __restrict__ src, u16* __restrict__ dst, int n) {
  int idx = blockIdx.x * 256 + threadIdx.x;
  if (idx < n) dst[idx] = f2bf(src[idx]);
}

// take 512-wide column slice [off, off+512) of rows with leading dim ld
__global__ void k_f2bf_sub(const float* __restrict__ src, u16* __restrict__ dst,
                           int n, int ld, int off) {
  int idx = blockIdx.x * 256 + threadIdx.x;
  if (idx < n) {
    int r = idx >> 9, c = idx & 511;
    dst[idx] = f2bf(src[(size_t)r * ld + off + c]);
  }
}

// A_emb[m= s*16+b][c] = bf16(emb[tok(b,s)][c]), tok = s==0 ? BOS(1) : target[b][s]
__global__ void k_gather(const float* __restrict__ emb, const int* __restrict__ tgt,
                         u16* __restrict__ dst, int n) {
  int idx = blockIdx.x * 256 + threadIdx.x;
  if (idx < n) {
    int m = idx >> 9, c = idx & 511;
    int b = m & 15, s = m >> 4;
    int tok = (s == 0) ? 1 : tgt[b * 128 + s];
    dst[idx] = f2bf(emb[(size_t)tok * 512 + c]);
  }
}

// ---------------- bf16 MFMA GEMM: C[m][n] = sum_k A[m][k]*B[n][k] + bias[n] ----------------
__global__ __launch_bounds__(256) void gemm_bf16(
    const u16* __restrict__ A, const u16* __restrict__ Bm,
    const float* __restrict__ bias, float* __restrict__ C,
    int ldc, int mode) {
  __shared__ u16 As[128 * 32];
  __shared__ u16 Bs[128 * 32];
  const int tid = threadIdx.x;
  const int lane = tid & 63;
  const int wave = tid >> 6;
  const int lr = lane & 15;
  const int quad = lane >> 4;
  const int wm = (wave >> 1) * 64;
  const int wn = (wave & 1) * 64;
  const int bm = blockIdx.y * 128;
  const int bn = blockIdx.x * 128;
  const int srow = tid >> 1;          // 0..127
  const int shalf = (tid & 1) * 16;   // 0 or 16

  f32x4 acc[4][4];
#pragma unroll
  for (int i = 0; i < 4; ++i)
#pragma unroll
    for (int j = 0; j < 4; ++j) acc[i][j] = (f32x4){0.f, 0.f, 0.f, 0.f};

  for (int kt = 0; kt < 16; ++kt) {
    const u16* gA = A + (size_t)(bm + srow) * 512 + kt * 32 + shalf;
    const u16* gB = Bm + (size_t)(bn + srow) * 512 + kt * 32 + shalf;
    uint4 a0 = *(const uint4*)gA;
    uint4 a1 = *(const uint4*)(gA + 8);
    uint4 b0 = *(const uint4*)gB;
    uint4 b1 = *(const uint4*)(gB + 8);
    __syncthreads();
    *(uint4*)&As[srow * 32 + shalf] = a0;
    *(uint4*)&As[srow * 32 + shalf + 8] = a1;
    *(uint4*)&Bs[srow * 32 + shalf] = b0;
    *(uint4*)&Bs[srow * 32 + shalf + 8] = b1;
    __syncthreads();
    bf16x8 af[4], bf[4];
#pragma unroll
    for (int i = 0; i < 4; ++i)
      af[i] = *(const bf16x8*)&As[(wm + i * 16 + lr) * 32 + quad * 8];
#pragma unroll
    for (int j = 0; j < 4; ++j)
      bf[j] = *(const bf16x8*)&Bs[(wn + j * 16 + lr) * 32 + quad * 8];
#pragma unroll
    for (int i = 0; i < 4; ++i)
#pragma unroll
      for (int j = 0; j < 4; ++j)
        acc[i][j] = __builtin_amdgcn_mfma_f32_16x16x32_bf16(af[i], bf[j], acc[i][j], 0, 0, 0);
  }

#pragma unroll
  for (int j = 0; j < 4; ++j) {
    int ng = bn + wn + j * 16 + lr;
    float bv = bias ? bias[ng] : 0.f;
#pragma unroll
    for (int i = 0; i < 4; ++i) {
      int mg0 = bm + wm + i * 16 + quad * 4;
#pragma unroll
      for (int r = 0; r < 4; ++r) {
        int mg = mg0 + r;
        float v = acc[i][j][r] + bv;
        if (mode == 0) {
          C[(size_t)mg * ldc + ng] = v;
        } else {
          if (mg < 2032) {
            int s = mg >> 4, b = mg & 15;
            C[(size_t)((b << 7) + s + 1) * 32000 + ng] = v;
          }
        }
      }
    }
  }
}

// ---------------- group-local (16-block) barrier ----------------
// Compiler drains vmcnt (incl. agent-scope stores) before each wave's
// s_barrier; thread0 re-drains + stores its flag at agent scope
// (MALL-coherent); wave 0 polls the group's 16 flags (one cache line).
__device__ __forceinline__ void gbar_g(u32* gb, int j, u32 phase) {
  __syncthreads();
  if (threadIdx.x == 0) {
    asm volatile("s_waitcnt vmcnt(0)" ::: "memory");
    __hip_atomic_store(&gb[j], phase, __ATOMIC_RELAXED, __HIP_MEMORY_SCOPE_AGENT);
  }
  if (threadIdx.x < 64) {
    for (;;) {
      u32 v = __hip_atomic_load(&gb[threadIdx.x & 15], __ATOMIC_RELAXED, __HIP_MEMORY_SCOPE_AGENT);
      if (__all(v >= phase)) break;
      __builtin_amdgcn_s_sleep(1);
    }
  }
  asm volatile("" ::: "memory");
  __syncthreads();
}

// ---------------- sequential decoder: 16 independent per-batch groups ----------------
// Group = 16 blocks sharing batch b (b = blockIdx.x>>4, member j = blockIdx.x&15).
// Block j owns: q rows [32j,32j+32) (8 per wave, fp32 REGISTERS — small enough
// to never spill), the rank-32 score partials for all 128 t, the 96 Whh rows
// its GRU slice needs (bf16 in LDS — 96 KB, never spills), and h slice
// [32j,32j+32).  Per step: PhaseA(h load, q regs matvec, tanh partials,
// gh LDS matvec) -> group bar -> PhaseB(gather partials, softmax, ctx, GRU,
// write h slice) -> group bar.
__global__ __launch_bounds__(256, 1) void seq_kernel(
    const float* __restrict__ Wq, const float* __restrict__ bq,
    const float* __restrict__ Wc, const float* __restrict__ bc,
    const float* __restrict__ Whh, const float* __restrict__ bhh,
    const float* __restrict__ h0, const int* __restrict__ mask,
    const float* __restrict__ ws_vt, const float* __restrict__ ws_P,
    const float* __restrict__ ws_gix, float* __restrict__ ws_hall,
    float* __restrict__ ws_part, u32* __restrict__ bars,
    float* __restrict__ outT) {
  const int k = blockIdx.x;        // 0..255
  const int b = k >> 4;            // batch
  const int j = k & 15;            // group member
  const int i0 = j << 5;           // h-slice / q-row-slice base
  const int tid = threadIdx.x;
  const int lane = tid & 63;
  const int wv = tid >> 6;

  __shared__ u16 Whh_s[96 * 512];  // 96 KB  bf16 Whh rows for this slice
  __shared__ u16 P_lds[128][96];   // 24 KB  P[b][t][jg-slice] bf16
  __shared__ float vt_s[32][128];  // 16 KB  vt[b][t][i0+rr] (transposed)
  __shared__ float h_l[512];
  __shared__ float q_l[32];
  __shared__ float gh_l[96];
  __shared__ float gi_l[96];
  __shared__ float s_lds[128];
  __shared__ float p_lds[128];
  __shared__ float Wc_s[32];
  __shared__ float bq_s[32];
  __shared__ float bhh_s[96];
  __shared__ int   m_l[128];

  // ---- step-invariant preloads ----
  // Each wave holds 8 Wq rows in fp32 registers (64 VGPR/lane — proven no-spill).
  float Wq_reg[8][8];
#pragma unroll
  for (int rr = 0; rr < 8; ++rr) {
    const float* wp = Wq + (size_t)(i0 + (wv << 3) + rr) * 512;
    const float4* w4 = (const float4*)(wp + (lane << 3));
    float4 a = w4[0], c = w4[1];
    Wq_reg[rr][0] = a.x; Wq_reg[rr][1] = a.y; Wq_reg[rr][2] = a.z; Wq_reg[rr][3] = a.w;
    Wq_reg[rr][4] = c.x; Wq_reg[rr][5] = c.y; Wq_reg[rr][6] = c.z; Wq_reg[rr][7] = c.w;
  }
  if (tid < 32) { Wc_s[tid] = Wc[i0 + tid]; bq_s[tid] = bq[i0 + tid]; }
  if (tid < 96) bhh_s[tid] = bhh[(tid >> 5) * 512 + i0 + (tid & 31)];
  if (tid < 128) m_l[tid] = mask[(b << 7) + tid];
  // Whh slice -> LDS bf16: rw in [0,96) maps to global row (rw>>5)*512 + i0 + (rw&31)
  for (int idx = tid; idx < 96 * 512; idx += 256) {
    int rw = idx >> 9, col = idx & 511;
    int grow = ((rw >> 5) << 9) + i0 + (rw & 31);
    Whh_s[idx] = f2bf(Whh[(size_t)grow * 512 + col]);
  }
  for (int idx = tid; idx < 128 * 96; idx += 256) {
    int t = idx / 96; int jj = idx - t * 96;
    int col = (jj >> 5) * 512 + i0 + (jj & 31);
    P_lds[t][jj] = f2bf(ws_P[(size_t)((b << 7) + t) * 1536 + col]);
  }
  for (int idx = tid; idx < 32 * 128; idx += 256) {
    int rr = idx >> 7, t = idx & 127;
    vt_s[rr][t] = ws_vt[(size_t)((b << 7) + t) * 512 + i0 + rr];
  }
  const float bc0 = bc[0];
  __syncthreads();

  u32* gb = bars + (b << 5);       // this group's private flag line
  u32 phase = 0;
  for (int s = 0; s < STEPS; ++s) {
    // ---- Phase A ----
    const float* hbase = (s == 0) ? (h0 + (b << 9))
                                  : (ws_hall + (size_t)(((s - 1) << 4) + b) * 512);
    h_l[tid] = ld_sys(hbase + tid);
    h_l[tid + 256] = ld_sys(hbase + tid + 256);
    __syncthreads();
    float hk[8];
    {
      const float4* h4 = (const float4*)&h_l[lane << 3];
      float4 a = h4[0], c = h4[1];
      hk[0] = a.x; hk[1] = a.y; hk[2] = a.z; hk[3] = a.w;
      hk[4] = c.x; hk[5] = c.y; hk[6] = c.z; hk[7] = c.w;
    }
    // q matvec: 8 register rows per wave
#pragma unroll
    for (int rr = 0; rr < 8; ++rr) {
      float p = Wq_reg[rr][0] * hk[0] + Wq_reg[rr][1] * hk[1]
              + Wq_reg[rr][2] * hk[2] + Wq_reg[rr][3] * hk[3]
              + Wq_reg[rr][4] * hk[4] + Wq_reg[rr][5] * hk[5]
              + Wq_reg[rr][6] * hk[6] + Wq_reg[rr][7] * hk[7];
      p = wred(p);
      if (lane == 0) {
        int rq = (wv << 3) + rr;
        q_l[rq] = p + bq_s[rq];
      }
    }
    __syncthreads();
    // rank-32 score partials: 2 threads per t, 16 tanh each
    {
      int t = tid >> 1, rh = (tid & 1) << 4;
      float part = 0.f;
#pragma unroll
      for (int u = 0; u < 16; ++u) {
        int rr = rh + u;
        part += Wc_s[rr] * tanh_fast(q_l[rr] + vt_s[rr][t]);
      }
      part += __shfl_xor(part, 1, 64);
      if (!(tid & 1)) st_sys(&ws_part[(size_t)(((b << 4) + j) << 7) + t], part);
    }
    // gh matvec from LDS bf16 (24 rows per wave) — overlaps partial straggle
#pragma unroll 4
    for (int rr = 0; rr < 24; ++rr) {
      int rw = wv * 24 + rr;
      bf16x8 w = *(const bf16x8*)&Whh_s[rw * 512 + (lane << 3)];
      const u32* wu = (const u32*)&w;
      float p = 0.f;
#pragma unroll
      for (int e = 0; e < 4; ++e) {
        u32 g = wu[e];
        union { u32 u; float f; } lo, hi;
        lo.u = g << 16; hi.u = g & 0xffff0000u;
        p += lo.f * hk[2 * e] + hi.f * hk[2 * e + 1];
      }
      p = wred(p);
      if (lane == 0) gh_l[rw] = p + bhh_s[rw];
    }
    gbar_g(gb, j, ++phase);

    // ---- Phase B: assemble scores, softmax, ctx, GRU update for my slice ----
    {
      int t = tid >> 1;
      int ib = (tid & 1) << 3;     // 2 threads per t, 8 partials each
      float sum = 0.f;
#pragma unroll
      for (int u = 0; u < 8; ++u)
        sum += ld_sys(&ws_part[(size_t)(((b << 4) + ib + u) << 7) + t]);
      sum += __shfl_xor(sum, 1, 64);
      if (!(tid & 1))
        s_lds[t] = m_l[t] ? (sum + bc0) : -3.4028234663852886e+38f;
    }
    __syncthreads();
    float vm = fmaxf(s_lds[lane], s_lds[64 + lane]);
#pragma unroll
    for (int mo = 32; mo > 0; mo >>= 1) vm = fmaxf(vm, __shfl_xor(vm, mo, 64));
    if (tid < 128) p_lds[tid] = __expf(s_lds[tid] - vm);
    __syncthreads();
    float vs = p_lds[lane] + p_lds[64 + lane];
#pragma unroll
    for (int mo = 32; mo > 0; mo >>= 1) vs += __shfl_xor(vs, mo, 64);
    float rsum = 1.0f / vs;
    if (tid < 96) {
      int jg = (tid >> 5) * 512 + i0 + (tid & 31);
      float acc = 0.f;
#pragma unroll 8
      for (int t = 0; t < 128; ++t) acc += p_lds[t] * bf2f(P_lds[t][tid]);
      gi_l[tid] = ws_gix[(size_t)((s << 4) + b) * 1536 + jg] + acc * rsum;
    }
    __syncthreads();
    if (tid < 32) {
      float rg = sigmoid_fast(gi_l[tid] + gh_l[tid]);
      float zg = sigmoid_fast(gi_l[32 + tid] + gh_l[32 + tid]);
      float ng = tanh_fast(gi_l[64 + tid] + rg * gh_l[64 + tid]);
      float hold = h_l[i0 + tid];
      float hn = (1.f - zg) * ng + zg * hold;
      st_sys(&ws_hall[(size_t)((s << 4) + b) * 512 + i0 + tid], hn);
    }
    gbar_g(gb, j, ++phase);
  }

  // hT output: member 0 of each group writes its batch's final h
  if (j == 0) {
    for (int i = tid; i < 512; i += 256)
      outT[(b << 9) + i] = ld_sys(&ws_hall[(size_t)(126 * 16 + b) * 512 + i]);
  }
}

// ---------------- launch ----------------
extern "C" void kernel_launch(void* const* d_in, const int* in_sizes, int n_in,
                              void* d_out, int out_size, void* d_ws, size_t ws_size,
                              hipStream_t stream) {
  const float* enc  = (const float*)d_in[0];
  const float* ehid = (const float*)d_in[1];
  const int*   mask = (const int*)d_in[2];
  const int*   tgt  = (const int*)d_in[3];
  const float* emb  = (const float*)d_in[4];
  const float* Wq   = (const float*)d_in[5];
  const float* bq   = (const float*)d_in[6];
  const float* Wv   = (const float*)d_in[7];
  const float* bv   = (const float*)d_in[8];
  const float* Wc   = (const float*)d_in[9];
  const float* bc   = (const float*)d_in[10];
  const float* Wih  = (const float*)d_in[11];
  const float* Whh  = (const float*)d_in[12];
  const float* bih  = (const float*)d_in[13];
  const float* bhh  = (const float*)d_in[14];
  const float* Wo   = (const float*)d_in[15];
  const float* bo   = (const float*)d_in[16];

  float* out = (float*)d_out;
  float* ws  = (float*)d_ws;
  float* vt   = ws + OFF_VT;
  float* P    = ws + OFF_P;
  float* gix  = ws + OFF_GIX;
  float* hall = ws + OFF_HALL;
  float* part = ws + OFF_PART;
  u32*   bars = (u32*)(ws + OFF_BAR);
  u16* A_enc = (u16*)(ws + OFF_AENC);
  u16* A_emb = (u16*)(ws + OFF_AEMB);
  u16* A_h   = (u16*)(ws + OFF_AH);
  u16* B_wv  = (u16*)(ws + OFF_BWV);
  u16* B_wi1 = (u16*)(ws + OFF_BWIH1);
  u16* B_wi2 = (u16*)(ws + OFF_BWIH2);
  u16* B_wo  = (u16*)(ws + OFF_BWO);

  k_init<<<2000, 256, 0, stream>>>(out, bars);
  k_f2bf<<<4096, 256, 0, stream>>>(enc, A_enc, 1048576);
  k_f2bf<<<1024, 256, 0, stream>>>(Wv, B_wv, 262144);
  k_f2bf_sub<<<3072, 256, 0, stream>>>(Wih, B_wi1, 786432, 1024, 0);
  k_f2bf_sub<<<3072, 256, 0, stream>>>(Wih, B_wi2, 786432, 1024, 512);
  k_f2bf<<<64000, 256, 0, stream>>>(Wo, B_wo, 16384000);
  k_gather<<<4064, 256, 0, stream>>>(emb, tgt, A_emb, 1040384);

  // vt = enc @ Wv.T + bv            [2048 x 512]
  gemm_bf16<<<dim3(4, 16), 256, 0, stream>>>(A_enc, B_wv, bv, vt, 512, 0);
  // P  = enc @ Wih[:,H:].T          [2048 x 1536]
  gemm_bf16<<<dim3(12, 16), 256, 0, stream>>>(A_enc, B_wi2, nullptr, P, 1536, 0);
  // gi_x = emb[toks] @ Wih[:,:H].T + bih   [2032 x 1536]
  gemm_bf16<<<dim3(12, 16), 256, 0, stream>>>(A_emb, B_wi1, bih, gix, 1536, 0);

  seq_kernel<<<256, 256, 0, stream>>>(Wq, bq, Wc, bc, Whh, bhh,
                                      ehid, mask, vt, P, gix, hall, part, bars,
                                      out + 65536000);

  k_f2bf<<<4064, 256, 0, stream>>>(hall, A_h, 1040384);
  // logits = h_all @ Wo.T + bo -> out[:,1:,:]
  gemm_bf16<<<dim3(250, 16), 256, 0, stream>>>(A_h, B_wo, bo, out, 32000, 1);
}

// Round 3
// 2723.225 us; speedup vs baseline: 1.2051x; 1.0036x over previous
//
#include <hip/hip_runtime.h>

typedef unsigned short u16;
typedef unsigned int u32;
typedef short bf16x8 __attribute__((ext_vector_type(8)));
typedef float f32x4 __attribute__((ext_vector_type(4)));

#define B_ 16
#define T_ 128
#define H_ 512
#define V_ 32000
#define G3 1536
#define STEPS 127

// ---------------- ws layout (float units) ----------------
#define OFF_VT    0u            // [2048][512]  m=b*128+t
#define OFF_P     1048576u      // [2048][1536] m=b*128+t
#define OFF_GIX   4194304u      // [2048][1536] m=s*16+b
#define OFF_HALL  7340032u      // [2048][512]  m=s*16+b
#define OFF_PART  8388608u      // [256][128] score partials
#define OFF_BAR   8423424u      // 512 u32: 16 groups x 32-u32 (ctr line + go line)
#define OFF_AENC  8431616u      // bf16 [2048][512]
#define OFF_AEMB  8955904u
#define OFF_AH    9480192u
#define OFF_BWV   10004480u     // bf16 [512][512]
#define OFF_BWIH1 10135552u     // bf16 [1536][512]
#define OFF_BWIH2 10528768u
#define OFF_BWO   10921984u     // bf16 [32000][512]

__device__ __forceinline__ u16 f2bf(float f) {
  union { float f; u32 u; } x; x.f = f;
  u32 r = x.u + 0x7fffu + ((x.u >> 16) & 1u);
  return (u16)(r >> 16);
}
__device__ __forceinline__ float bf2f(u16 u) {
  union { u32 u; float f; } x; x.u = ((u32)u) << 16;
  return x.f;
}
__device__ __forceinline__ float wred(float v) {
#pragma unroll
  for (int off = 32; off > 0; off >>= 1) v += __shfl_down(v, off, 64);
  return v; // valid in lane 0
}
// fast tanh via v_exp_f32: tanh(x) = (e^{2x}-1)/(e^{2x}+1), clamped
__device__ __forceinline__ float tanh_fast(float x) {
  float cx = fminf(8.f, fmaxf(-8.f, x));
  float e = __expf(2.f * cx);
  return (e - 1.f) / (e + 1.f);
}
__device__ __forceinline__ float sigmoid_fast(float x) {
  return 1.f / (1.f + __expf(-x));
}

// MALL-coherent scalar exchange: relaxed agent-scope atomics bypass stale
// L1/per-XCD-L2 and serialize at the Infinity Cache. No fences needed.
__device__ __forceinline__ void st_sys(float* p, float v) {
  __hip_atomic_store(p, v, __ATOMIC_RELAXED, __HIP_MEMORY_SCOPE_AGENT);
}
__device__ __forceinline__ float ld_sys(const float* p) {
  return __hip_atomic_load(p, __ATOMIC_RELAXED, __HIP_MEMORY_SCOPE_AGENT);
}

// ---------------- small utility kernels ----------------
__global__ void k_init(float* __restrict__ out, u32* __restrict__ bars) {
  int idx = blockIdx.x * 256 + threadIdx.x;
  if (idx < 512000) {            // out[:,0,:] = 0
    int b = idx / 32000; int v = idx - b * 32000;
    out[(size_t)b * 4096000 + v] = 0.f;
  }
  if (idx < 512) bars[idx] = 0u;
}

__global__ void k_f2bf(const float* __restrict__ src, u16* __restrict__ dst, int n) {
  int idx = blockIdx.x * 256 + threadIdx.x;
  if (idx < n) dst[idx] = f2bf(src[idx]);
}

// take 512-wide column slice [off, off+512) of rows with leading dim ld
__global__ void k_f2bf_sub(const float* __restrict__ src, u16* __restrict__ dst,
                           int n, int ld, int off) {
  int idx = blockIdx.x * 256 + threadIdx.x;
  if (idx < n) {
    int r = idx >> 9, c = idx & 511;
    dst[idx] = f2bf(src[(size_t)r * ld + off + c]);
  }
}

// A_emb[m= s*16+b][c] = bf16(emb[tok(b,s)][c]), tok = s==0 ? BOS(1) : target[b][s]
__global__ void k_gather(const float* __restrict__ emb, const int* __restrict__ tgt,
                         u16* __restrict__ dst, int n) {
  int idx = blockIdx.x * 256 + threadIdx.x;
  if (idx < n) {
    int m = idx >> 9, c = idx & 511;
    int b = m & 15, s = m >> 4;
    int tok = (s == 0) ? 1 : tgt[b * 128 + s];
    dst[idx] = f2bf(emb[(size_t)tok * 512 + c]);
  }
}

// ---------------- bf16 MFMA GEMM: C[m][n] = sum_k A[m][k]*B[n][k] + bias[n] ----------------
__global__ __launch_bounds__(256) void gemm_bf16(
    const u16* __restrict__ A, const u16* __restrict__ Bm,
    const float* __restrict__ bias, float* __restrict__ C,
    int ldc, int mode) {
  __shared__ u16 As[128 * 32];
  __shared__ u16 Bs[128 * 32];
  const int tid = threadIdx.x;
  const int lane = tid & 63;
  const int wave = tid >> 6;
  const int lr = lane & 15;
  const int quad = lane >> 4;
  const int wm = (wave >> 1) * 64;
  const int wn = (wave & 1) * 64;
  const int bm = blockIdx.y * 128;
  const int bn = blockIdx.x * 128;
  const int srow = tid >> 1;          // 0..127
  const int shalf = (tid & 1) * 16;   // 0 or 16

  f32x4 acc[4][4];
#pragma unroll
  for (int i = 0; i < 4; ++i)
#pragma unroll
    for (int j = 0; j < 4; ++j) acc[i][j] = (f32x4){0.f, 0.f, 0.f, 0.f};

  for (int kt = 0; kt < 16; ++kt) {
    const u16* gA = A + (size_t)(bm + srow) * 512 + kt * 32 + shalf;
    const u16* gB = Bm + (size_t)(bn + srow) * 512 + kt * 32 + shalf;
    uint4 a0 = *(const uint4*)gA;
    uint4 a1 = *(const uint4*)(gA + 8);
    uint4 b0 = *(const uint4*)gB;
    uint4 b1 = *(const uint4*)(gB + 8);
    __syncthreads();
    *(uint4*)&As[srow * 32 + shalf] = a0;
    *(uint4*)&As[srow * 32 + shalf + 8] = a1;
    *(uint4*)&Bs[srow * 32 + shalf] = b0;
    *(uint4*)&Bs[srow * 32 + shalf + 8] = b1;
    __syncthreads();
    bf16x8 af[4], bf[4];
#pragma unroll
    for (int i = 0; i < 4; ++i)
      af[i] = *(const bf16x8*)&As[(wm + i * 16 + lr) * 32 + quad * 8];
#pragma unroll
    for (int j = 0; j < 4; ++j)
      bf[j] = *(const bf16x8*)&Bs[(wn + j * 16 + lr) * 32 + quad * 8];
#pragma unroll
    for (int i = 0; i < 4; ++i)
#pragma unroll
      for (int j = 0; j < 4; ++j)
        acc[i][j] = __builtin_amdgcn_mfma_f32_16x16x32_bf16(af[i], bf[j], acc[i][j], 0, 0, 0);
  }

#pragma unroll
  for (int j = 0; j < 4; ++j) {
    int ng = bn + wn + j * 16 + lr;
    float bv = bias ? bias[ng] : 0.f;
#pragma unroll
    for (int i = 0; i < 4; ++i) {
      int mg0 = bm + wm + i * 16 + quad * 4;
#pragma unroll
      for (int r = 0; r < 4; ++r) {
        int mg = mg0 + r;
        float v = acc[i][j][r] + bv;
        if (mode == 0) {
          C[(size_t)mg * ldc + ng] = v;
        } else {
          if (mg < 2032) {
            int s = mg >> 4, b = mg & 15;
            C[(size_t)((b << 7) + s + 1) * 32000 + ng] = v;
          }
        }
      }
    }
  }
}

// ---------------- group-local (16-block) barrier: counter + go-word ----------------
// gb[0]  (line 0): monotone arrival counter (atomicAdd, agent scope)
// gb[16] (line 1): go word = last completed phase
// __syncthreads() drains each wave's vmcnt (sc1 stores ack'd at MALL) before
// thread0 arrives; arrival atomic thus orders after all block data stores.
// Only thread0 polls the single go word (s_sleep backoff) -> no MALL line
// contention; release store doesn't queue behind polls.
__device__ __forceinline__ void gbar_g(u32* gb, u32 phase) {
  __syncthreads();
  if (threadIdx.x == 0) {
    asm volatile("s_waitcnt vmcnt(0)" ::: "memory");
    u32 old = __hip_atomic_fetch_add(&gb[0], 1u, __ATOMIC_RELAXED, __HIP_MEMORY_SCOPE_AGENT);
    if (old == phase * 16u - 1u)
      __hip_atomic_store(&gb[16], phase, __ATOMIC_RELAXED, __HIP_MEMORY_SCOPE_AGENT);
    while (__hip_atomic_load(&gb[16], __ATOMIC_RELAXED, __HIP_MEMORY_SCOPE_AGENT) < phase)
      __builtin_amdgcn_s_sleep(2);
  }
  asm volatile("" ::: "memory");
  __syncthreads();
}

// ---------------- sequential decoder: 16 independent per-batch groups ----------------
// Group = 16 blocks sharing batch b (b = blockIdx.x>>4, member j = blockIdx.x&15).
// Block j owns: q rows [32j,32j+32) (8 per wave, fp32 registers), the rank-32
// score partials for all 128 t, the 96 Whh rows its GRU slice needs (bf16 LDS),
// and h slice [32j,32j+32).  Per step: PhaseA(h load, q matvec, tanh partials,
// gh matvec) -> group bar -> PhaseB(gather partials, softmax, ctx, GRU, write
// h slice) -> group bar.
__global__ __launch_bounds__(256, 1) void seq_kernel(
    const float* __restrict__ Wq, const float* __restrict__ bq,
    const float* __restrict__ Wc, const float* __restrict__ bc,
    const float* __restrict__ Whh, const float* __restrict__ bhh,
    const float* __restrict__ h0, const int* __restrict__ mask,
    const float* __restrict__ ws_vt, const float* __restrict__ ws_P,
    const float* __restrict__ ws_gix, float* __restrict__ ws_hall,
    float* __restrict__ ws_part, u32* __restrict__ bars,
    float* __restrict__ outT) {
  const int k = blockIdx.x;        // 0..255
  const int b = k >> 4;            // batch
  const int j = k & 15;            // group member
  const int i0 = j << 5;           // h-slice / q-row-slice base
  const int tid = threadIdx.x;
  const int lane = tid & 63;
  const int wv = tid >> 6;

  __shared__ u16 Whh_s[96 * 512];  // 96 KB  bf16 Whh rows for this slice
  __shared__ u16 P_lds[128][96];   // 24 KB  P[b][t][jg-slice] bf16
  __shared__ float vt_s[32][128];  // 16 KB  vt[b][t][i0+rr] (transposed)
  __shared__ float h_l[512];
  __shared__ float q_l[32];
  __shared__ float gh_l[96];
  __shared__ float gi_l[96];
  __shared__ float s_lds[128];
  __shared__ float p_lds[128];
  __shared__ float Wc_s[32];
  __shared__ float bq_s[32];
  __shared__ float bhh_s[96];
  __shared__ int   m_l[128];

  // ---- step-invariant preloads ----
  // Each wave holds 8 Wq rows in fp32 registers (64 VGPR/lane — no spill).
  float Wq_reg[8][8];
#pragma unroll
  for (int rr = 0; rr < 8; ++rr) {
    const float* wp = Wq + (size_t)(i0 + (wv << 3) + rr) * 512;
    const float4* w4 = (const float4*)(wp + (lane << 3));
    float4 a = w4[0], c = w4[1];
    Wq_reg[rr][0] = a.x; Wq_reg[rr][1] = a.y; Wq_reg[rr][2] = a.z; Wq_reg[rr][3] = a.w;
    Wq_reg[rr][4] = c.x; Wq_reg[rr][5] = c.y; Wq_reg[rr][6] = c.z; Wq_reg[rr][7] = c.w;
  }
  if (tid < 32) { Wc_s[tid] = Wc[i0 + tid]; bq_s[tid] = bq[i0 + tid]; }
  if (tid < 96) bhh_s[tid] = bhh[(tid >> 5) * 512 + i0 + (tid & 31)];
  if (tid < 128) m_l[tid] = mask[(b << 7) + tid];
  // Whh slice -> LDS bf16: rw in [0,96) maps to global row (rw>>5)*512 + i0 + (rw&31)
  for (int idx = tid; idx < 96 * 512; idx += 256) {
    int rw = idx >> 9, col = idx & 511;
    int grow = ((rw >> 5) << 9) + i0 + (rw & 31);
    Whh_s[idx] = f2bf(Whh[(size_t)grow * 512 + col]);
  }
  for (int idx = tid; idx < 128 * 96; idx += 256) {
    int t = idx / 96; int jj = idx - t * 96;
    int col = (jj >> 5) * 512 + i0 + (jj & 31);
    P_lds[t][jj] = f2bf(ws_P[(size_t)((b << 7) + t) * 1536 + col]);
  }
  for (int idx = tid; idx < 32 * 128; idx += 256) {
    int rr = idx >> 7, t = idx & 127;
    vt_s[rr][t] = ws_vt[(size_t)((b << 7) + t) * 512 + i0 + rr];
  }
  const float bc0 = bc[0];
  __syncthreads();

  u32* gb = bars + (b << 5);       // this group's private ctr/go lines
  u32 phase = 0;
  for (int s = 0; s < STEPS; ++s) {
    // ---- Phase A ----
    const float* hbase = (s == 0) ? (h0 + (b << 9))
                                  : (ws_hall + (size_t)(((s - 1) << 4) + b) * 512);
    h_l[tid] = ld_sys(hbase + tid);
    h_l[tid + 256] = ld_sys(hbase + tid + 256);
    // prefetch this step's gi_x value (plain load, no barrier dependency)
    float gix_pre = 0.f;
    if (tid < 96) {
      int jg = (tid >> 5) * 512 + i0 + (tid & 31);
      gix_pre = ws_gix[(size_t)((s << 4) + b) * 1536 + jg];
    }
    __syncthreads();
    float hk[8];
    {
      const float4* h4 = (const float4*)&h_l[lane << 3];
      float4 a = h4[0], c = h4[1];
      hk[0] = a.x; hk[1] = a.y; hk[2] = a.z; hk[3] = a.w;
      hk[4] = c.x; hk[5] = c.y; hk[6] = c.z; hk[7] = c.w;
    }
    // q matvec: 8 register rows per wave
#pragma unroll
    for (int rr = 0; rr < 8; ++rr) {
      float p = Wq_reg[rr][0] * hk[0] + Wq_reg[rr][1] * hk[1]
              + Wq_reg[rr][2] * hk[2] + Wq_reg[rr][3] * hk[3]
              + Wq_reg[rr][4] * hk[4] + Wq_reg[rr][5] * hk[5]
              + Wq_reg[rr][6] * hk[6] + Wq_reg[rr][7] * hk[7];
      p = wred(p);
      if (lane == 0) {
        int rq = (wv << 3) + rr;
        q_l[rq] = p + bq_s[rq];
      }
    }
    __syncthreads();
    // rank-32 score partials: 2 threads per t, 16 tanh each
    {
      int t = tid >> 1, rh = (tid & 1) << 4;
      float part = 0.f;
#pragma unroll
      for (int u = 0; u < 16; ++u) {
        int rr = rh + u;
        part += Wc_s[rr] * tanh_fast(q_l[rr] + vt_s[rr][t]);
      }
      part += __shfl_xor(part, 1, 64);
      if (!(tid & 1)) st_sys(&ws_part[(size_t)(((b << 4) + j) << 7) + t], part);
    }
    // gh matvec from LDS bf16 (24 rows per wave) — overlaps partial straggle
#pragma unroll 4
    for (int rr = 0; rr < 24; ++rr) {
      int rw = wv * 24 + rr;
      bf16x8 w = *(const bf16x8*)&Whh_s[rw * 512 + (lane << 3)];
      const u32* wu = (const u32*)&w;
      float p = 0.f;
#pragma unroll
      for (int e = 0; e < 4; ++e) {
        u32 g = wu[e];
        union { u32 u; float f; } lo, hi;
        lo.u = g << 16; hi.u = g & 0xffff0000u;
        p += lo.f * hk[2 * e] + hi.f * hk[2 * e + 1];
      }
      p = wred(p);
      if (lane == 0) gh_l[rw] = p + bhh_s[rw];
    }
    gbar_g(gb, ++phase);

    // ---- Phase B: assemble scores, softmax, ctx, GRU update for my slice ----
    {
      int t = tid >> 1;
      int ib = (tid & 1) << 3;     // 2 threads per t, 8 partials each
      float sum = 0.f;
#pragma unroll
      for (int u = 0; u < 8; ++u)
        sum += ld_sys(&ws_part[(size_t)(((b << 4) + ib + u) << 7) + t]);
      sum += __shfl_xor(sum, 1, 64);
      if (!(tid & 1))
        s_lds[t] = m_l[t] ? (sum + bc0) : -3.4028234663852886e+38f;
    }
    __syncthreads();
    float vm = fmaxf(s_lds[lane], s_lds[64 + lane]);
#pragma unroll
    for (int mo = 32; mo > 0; mo >>= 1) vm = fmaxf(vm, __shfl_xor(vm, mo, 64));
    if (tid < 128) p_lds[tid] = __expf(s_lds[tid] - vm);
    __syncthreads();
    float vs = p_lds[lane] + p_lds[64 + lane];
#pragma unroll
    for (int mo = 32; mo > 0; mo >>= 1) vs += __shfl_xor(vs, mo, 64);
    float rsum = 1.0f / vs;
    if (tid < 96) {
      // 4-way split accumulator: breaks the 128-long serial FMA chain
      float a0 = 0.f, a1 = 0.f, a2 = 0.f, a3 = 0.f;
#pragma unroll 8
      for (int t = 0; t < 128; t += 4) {
        a0 += p_lds[t]     * bf2f(P_lds[t][tid]);
        a1 += p_lds[t + 1] * bf2f(P_lds[t + 1][tid]);
        a2 += p_lds[t + 2] * bf2f(P_lds[t + 2][tid]);
        a3 += p_lds[t + 3] * bf2f(P_lds[t + 3][tid]);
      }
      float acc = (a0 + a1) + (a2 + a3);
      gi_l[tid] = gix_pre + acc * rsum;
    }
    __syncthreads();
    if (tid < 32) {
      float rg = sigmoid_fast(gi_l[tid] + gh_l[tid]);
      float zg = sigmoid_fast(gi_l[32 + tid] + gh_l[32 + tid]);
      float ng = tanh_fast(gi_l[64 + tid] + rg * gh_l[64 + tid]);
      float hold = h_l[i0 + tid];
      float hn = (1.f - zg) * ng + zg * hold;
      st_sys(&ws_hall[(size_t)((s << 4) + b) * 512 + i0 + tid], hn);
    }
    gbar_g(gb, ++phase);
  }

  // hT output: member 0 of each group writes its batch's final h
  if (j == 0) {
    for (int i = tid; i < 512; i += 256)
      outT[(b << 9) + i] = ld_sys(&ws_hall[(size_t)(126 * 16 + b) * 512 + i]);
  }
}

// ---------------- launch ----------------
extern "C" void kernel_launch(void* const* d_in, const int* in_sizes, int n_in,
                              void* d_out, int out_size, void* d_ws, size_t ws_size,
                              hipStream_t stream) {
  const float* enc  = (const float*)d_in[0];
  const float* ehid = (const float*)d_in[1];
  const int*   mask = (const int*)d_in[2];
  const int*   tgt  = (const int*)d_in[3];
  const float* emb  = (const float*)d_in[4];
  const float* Wq   = (const float*)d_in[5];
  const float* bq   = (const float*)d_in[6];
  const float* Wv   = (const float*)d_in[7];
  const float* bv   = (const float*)d_in[8];
  const float* Wc   = (const float*)d_in[9];
  const float* bc   = (const float*)d_in[10];
  const float* Wih  = (const float*)d_in[11];
  const float* Whh  = (const float*)d_in[12];
  const float* bih  = (const float*)d_in[13];
  const float* bhh  = (const float*)d_in[14];
  const float* Wo   = (const float*)d_in[15];
  const float* bo   = (const float*)d_in[16];

  float* out = (float*)d_out;
  float* ws  = (float*)d_ws;
  float* vt   = ws + OFF_VT;
  float* P    = ws + OFF_P;
  float* gix  = ws + OFF_GIX;
  float* hall = ws + OFF_HALL;
  float* part = ws + OFF_PART;
  u32*   bars = (u32*)(ws + OFF_BAR);
  u16* A_enc = (u16*)(ws + OFF_AENC);
  u16* A_emb = (u16*)(ws + OFF_AEMB);
  u16* A_h   = (u16*)(ws + OFF_AH);
  u16* B_wv  = (u16*)(ws + OFF_BWV);
  u16* B_wi1 = (u16*)(ws + OFF_BWIH1);
  u16* B_wi2 = (u16*)(ws + OFF_BWIH2);
  u16* B_wo  = (u16*)(ws + OFF_BWO);

  k_init<<<2000, 256, 0, stream>>>(out, bars);
  k_f2bf<<<4096, 256, 0, stream>>>(enc, A_enc, 1048576);
  k_f2bf<<<1024, 256, 0, stream>>>(Wv, B_wv, 262144);
  k_f2bf_sub<<<3072, 256, 0, stream>>>(Wih, B_wi1, 786432, 1024, 0);
  k_f2bf_sub<<<3072, 256, 0, stream>>>(Wih, B_wi2, 786432, 1024, 512);
  k_f2bf<<<64000, 256, 0, stream>>>(Wo, B_wo, 16384000);
  k_gather<<<4064, 256, 0, stream>>>(emb, tgt, A_emb, 1040384);

  // vt = enc @ Wv.T + bv            [2048 x 512]
  gemm_bf16<<<dim3(4, 16), 256, 0, stream>>>(A_enc, B_wv, bv, vt, 512, 0);
  // P  = enc @ Wih[:,H:].T          [2048 x 1536]
  gemm_bf16<<<dim3(12, 16), 256, 0, stream>>>(A_enc, B_wi2, nullptr, P, 1536, 0);
  // gi_x = emb[toks] @ Wih[:,:H].T + bih   [2032 x 1536]
  gemm_bf16<<<dim3(12, 16), 256, 0, stream>>>(A_emb, B_wi1, bih, gix, 1536, 0);

  seq_kernel<<<256, 256, 0, stream>>>(Wq, bq, Wc, bc, Whh, bhh,
                                      ehid, mask, vt, P, gix, hall, part, bars,
                                      out + 65536000);

  k_f2bf<<<4064, 256, 0, stream>>>(hall, A_h, 1040384);
  // logits = h_all @ Wo.T + bo -> out[:,1:,:]
  gemm_bf16<<<dim3(250, 16), 256, 0, stream>>>(A_h, B_wo, bo, out, 32000, 1);
}